// Round 6
// baseline (978.991 us; speedup 1.0000x reference)
//
#include <hip/hip_runtime.h>
#include <math.h>

#define DD   128
#define NB   32
#define NT   256
#define NBLK 4      // DD / NB
#define SPACK 8448  // rowoff(128) floats = 33.8 KB packed lower triangle

// Packed lower-triangle layout, rows 16B-aligned.
// Row i (group g=i>>2) gets 4*(g+1) float slots; element [i][c] at rowoff(i)+c.
__device__ __forceinline__ int rowoff(int i) {
    const int g = i >> 2, m = i & 3;
    return 8*g*(g+1) + 4*m*(g+1);
}

// mt[r][c] += dot(a[r], b[c])   (both operands k-major in the float4 lanes)
__device__ __forceinline__ void dotacc(float mt[4][4], const float4 a[4], const float4 b[4]) {
    #pragma unroll
    for (int r = 0; r < 4; ++r) {
        #pragma unroll
        for (int c = 0; c < 4; ++c)
            mt[r][c] = fmaf(a[r].x, b[c].x, fmaf(a[r].y, b[c].y,
                       fmaf(a[r].z, b[c].z, fmaf(a[r].w, b[c].w, mt[r][c]))));
    }
}

// mt[r][c] += sum_e a[r](e) * b[e](c)   (a k-major in lanes, b row-major)
__device__ __forceinline__ void gemmacc(float mt[4][4], const float4 a[4], const float4 b[4]) {
    #pragma unroll
    for (int r = 0; r < 4; ++r) {
        mt[r][0] = fmaf(a[r].x, b[0].x, fmaf(a[r].y, b[1].x, fmaf(a[r].z, b[2].x, fmaf(a[r].w, b[3].x, mt[r][0]))));
        mt[r][1] = fmaf(a[r].x, b[0].y, fmaf(a[r].y, b[1].y, fmaf(a[r].z, b[2].y, fmaf(a[r].w, b[3].y, mt[r][1]))));
        mt[r][2] = fmaf(a[r].x, b[0].z, fmaf(a[r].y, b[1].z, fmaf(a[r].z, b[2].z, fmaf(a[r].w, b[3].z, mt[r][2]))));
        mt[r][3] = fmaf(a[r].x, b[0].w, fmaf(a[r].y, b[1].w, fmaf(a[r].z, b[2].w, fmaf(a[r].w, b[3].w, mt[r][3]))));
    }
}

// ---------------------------------------------------------------------------
// winv[d][p] = 1 / (inv(b_covs[p]))_{dd}
// Blocked Cholesky; each 32x32 diag block factored AND inverted in-wave, so
// panel solve + triangular inversion are parallel register-tiled GEMMs.
// launch_bounds(256,3): 170-VGPR cap -> NO scratch spill (R5's (256,4)=128
// cap spilled ~550 MB to HBM); LDS 34.8 KB still permits 3 blocks/CU.
// ---------------------------------------------------------------------------
__global__ __launch_bounds__(NT, 3) void diag_inv_kernel(
    const float* __restrict__ covs,   // [P][D][D]
    const int*   __restrict__ ctp,
    float*       __restrict__ winv,   // [D][P]
    int P)
{
    const int ct = *ctp;
    if (ct != 1) return;              // uniform, before any barrier

    const int p   = blockIdx.x;
    const int tid = threadIdx.x;

    __shared__ __align__(16) float S[SPACK];
    __shared__ __align__(16) float invd[DD];
    __shared__ __align__(16) float colsum[DD];

    // ---- Load lower triangle (row-prefix reads are coalesced) ----
    const float* Ap = covs + (size_t)p * DD * DD;
    #pragma unroll
    for (int it = 0; it < 16; ++it) {
        const int w   = it * NT + tid;       // square float4 slot 0..4095
        const int row = w >> 5;
        const int c4  = w & 31;
        if (c4 <= (row >> 2))                // fills the full allocated row slots
            *(float4*)&S[rowoff(row) + 4*c4] =
                *(const float4*)(Ap + (size_t)row * DD + 4*c4);
    }
    if (tid < DD) colsum[tid] = 0.0f;
    __syncthreads();

    // ================= Phase 1 =================
    for (int jb = 0; jb < NBLK; ++jb) {
        const int J = jb * NB;

        // ---- Stage A: factor diag block (wave-0 lanes 0..31, lockstep) ----
        if (tid < NB) {
            float* myrow = &S[rowoff(J + tid) + J];
            for (int jj = 0; jj < NB; ++jj) {
                if (tid >= jj) {
                    const float* jrow = &S[rowoff(J + jj) + J];
                    float4 sa = {0,0,0,0}, da = {0,0,0,0};
                    const int j4 = jj & ~3;
                    for (int k = 0; k < j4; k += 4) {
                        float4 a = *(const float4*)(myrow + k);
                        float4 b = *(const float4*)(jrow + k);
                        sa.x = fmaf(a.x,b.x,sa.x); sa.y = fmaf(a.y,b.y,sa.y);
                        sa.z = fmaf(a.z,b.z,sa.z); sa.w = fmaf(a.w,b.w,sa.w);
                        da.x = fmaf(b.x,b.x,da.x); da.y = fmaf(b.y,b.y,da.y);
                        da.z = fmaf(b.z,b.z,da.z); da.w = fmaf(b.w,b.w,da.w);
                    }
                    float s = (sa.x+sa.y)+(sa.z+sa.w);
                    float d = (da.x+da.y)+(da.z+da.w);
                    for (int k = j4; k < jj; ++k) {
                        float a = myrow[k], b = jrow[k];
                        s = fmaf(a,b,s); d = fmaf(b,b,d);
                    }
                    s = myrow[jj] - s;
                    d = jrow[jj]  - d;                   // pivot
                    float r = rsqrtf(d);
                    r = r * (1.5f - 0.5f * d * r * r);   // Newton step
                    if (tid == jj) { invd[J + jj] = r; myrow[jj] = d * r; }
                    else            myrow[jj] = s * r;
                }
            }
        }
        // ---- Stage A2: W_bb = L_bb^{-1} (same wave; z in regs; writes after
        //      all reads -> no race). Stored over L_bb incl diag. ----
        if (tid < NB) {
            float z[NB];
            #pragma unroll
            for (int k = 0; k < NB; ++k) z[k] = (k == tid) ? invd[J + tid] : 0.0f;
            #pragma unroll
            for (int rr = 1; rr < NB; ++rr) {
                const float* lrow = &S[rowoff(J + rr) + J];
                float4 a4 = {0,0,0,0};
                #pragma unroll
                for (int k4 = 0; k4 < (rr & ~3); k4 += 4) {
                    float4 l = *(const float4*)(lrow + k4);
                    a4.x = fmaf(l.x, z[k4+0], a4.x);
                    a4.y = fmaf(l.y, z[k4+1], a4.y);
                    a4.z = fmaf(l.z, z[k4+2], a4.z);
                    a4.w = fmaf(l.w, z[k4+3], a4.w);
                }
                float s = (a4.x+a4.y)+(a4.z+a4.w);
                #pragma unroll
                for (int k = (rr & ~3); k < rr; ++k)
                    s = fmaf(lrow[k], z[k], s);
                const float v = -invd[J + rr] * s;
                if (rr > tid) z[rr] = v;
            }
            float cs = 0.0f;
            #pragma unroll
            for (int rr = 0; rr < NB; ++rr) {
                if (rr >= tid) {
                    S[rowoff(J + rr) + J + tid] = z[rr];
                    cs = fmaf(z[rr], z[rr], cs);
                }
            }
            colsum[J + tid] += cs;     // sole writer of this column right now
        }
        __syncthreads();

        const int nrows = DD - (J + NB);      // 96, 64, 32, 0
        if (nrows > 0) {
            // ---- Stage B: panel L_p = A_p * W_bb^T  (parallel GEMM) ----
            const int ntileB = (nrows >> 2) * 8;
            const int tr = tid >> 3, tc = tid & 7;
            float bt[4][4] = {{0,0,0,0},{0,0,0,0},{0,0,0,0},{0,0,0,0}};
            int prB = 0, saB = 0;
            if (tid < ntileB) {
                prB = J + NB + 4*tr;
                saB = 4*((prB >> 2) + 1);
                const float* A0 = &S[rowoff(prB) + J];
                const int wr = J + 4*tc;
                const int sw = 4*((wr >> 2) + 1);
                const float* W0 = &S[rowoff(wr) + J];
                float4 av[4], wv[4];
                for (int k4 = 0; k4 < 4*tc; k4 += 4) {
                    #pragma unroll
                    for (int r = 0; r < 4; ++r) av[r] = *(const float4*)(A0 + r*saB + k4);
                    #pragma unroll
                    for (int c = 0; c < 4; ++c) wv[c] = *(const float4*)(W0 + c*sw + k4);
                    dotacc(bt, av, wv);
                }
                {   // chunk k4 == 4*tc: W[c][k] valid only for k-lane e <= c
                    const int k4 = 4*tc;
                    #pragma unroll
                    for (int r = 0; r < 4; ++r) av[r] = *(const float4*)(A0 + r*saB + k4);
                    #pragma unroll
                    for (int c = 0; c < 4; ++c) wv[c] = *(const float4*)(W0 + c*sw + k4);
                    wv[0].y = wv[0].z = wv[0].w = 0.f;
                    wv[1].z = wv[1].w = 0.f;
                    wv[2].w = 0.f;
                    dotacc(bt, av, wv);
                }
            }
            __syncthreads();               // all reads of A_p done
            if (tid < ntileB) {
                float* O0 = &S[rowoff(prB) + J + 4*tc];
                #pragma unroll
                for (int r = 0; r < 4; ++r) {
                    float4 o = {bt[r][0], bt[r][1], bt[r][2], bt[r][3]};
                    *(float4*)(O0 + r*saB) = o;
                }
            }
            __syncthreads();

            // ---- Stage C: SYRK trailing update ----
            const int mtC = nrows >> 2;
            const int ntileC = mtC * (mtC + 1) / 2;
            for (int t = tid; t < ntileC; t += NT) {
                int bi = (int)((sqrtf(8.0f * (float)t + 1.0f) - 1.0f) * 0.5f);
                while ((bi + 1) * (bi + 2) / 2 <= t) ++bi;
                while (bi * (bi + 1) / 2 > t)       --bi;
                const int bj = t - bi * (bi + 1) / 2;
                const int pi_ = J + NB + 4*bi, pj_ = J + NB + 4*bj;
                const int sa = 4*((pi_ >> 2) + 1), sb = 4*((pj_ >> 2) + 1);
                const float* Ar = &S[rowoff(pi_) + J];
                const float* Br = &S[rowoff(pj_) + J];
                float acc[4][4] = {{0,0,0,0},{0,0,0,0},{0,0,0,0},{0,0,0,0}};
                float4 av[4], bv[4];
                #pragma unroll
                for (int k4 = 0; k4 < NB; k4 += 4) {
                    #pragma unroll
                    for (int r = 0; r < 4; ++r) av[r] = *(const float4*)(Ar + r*sa + k4);
                    #pragma unroll
                    for (int c = 0; c < 4; ++c) bv[c] = *(const float4*)(Br + c*sb + k4);
                    dotacc(acc, av, bv);
                }
                if (bi != bj) {
                    #pragma unroll
                    for (int r = 0; r < 4; ++r) {
                        float* o = &S[rowoff(pi_) + r*sa + pj_];
                        float4 v = *(const float4*)o;
                        v.x -= acc[r][0]; v.y -= acc[r][1];
                        v.z -= acc[r][2]; v.w -= acc[r][3];
                        *(float4*)o = v;
                    }
                } else {     // diagonal tile: guarded scalar RMW (packed layout!)
                    #pragma unroll
                    for (int r = 0; r < 4; ++r)
                        #pragma unroll
                        for (int c = 0; c < 4; ++c)
                            if (4*bj + c <= 4*bi + r)
                                S[rowoff(pi_) + r*sa + pj_ + c] -= acc[r][c];
                }
            }
            __syncthreads();
        }
    }

    // ================= Phase 2: W_ij = -W_ii * (sum_k L_ik W_kj) ============
    for (int i = 1; i < NBLK; ++i) {
        const int Ji = i * NB;
        const int jblk = tid >> 6;
        const int tt = tid & 63, tr = tt >> 3, tc = tt & 7;
        const bool act = (tid < i * 64);
        const int Jj = jblk * NB;
        const int orow = Ji + 4*tr;
        const int so = 4*((orow >> 2) + 1);
        const int obase = rowoff(orow);
        float mt[4][4] = {{0,0,0,0},{0,0,0,0},{0,0,0,0},{0,0,0,0}};

        if (act) {
            float4 lv[4], wv[4];
            {   // k == jblk: triangular W_jj. Valid kappa >= col -> chunk
                // k4==4tc masked (row e keeps cols c<=e), then k4>4tc full.
                const int k4 = 4*tc;
                #pragma unroll
                for (int r = 0; r < 4; ++r) lv[r] = *(const float4*)(&S[obase + r*so + Jj + k4]);
                const int wr = Jj + k4;
                const int sw = 4*((wr >> 2) + 1);
                #pragma unroll
                for (int e = 0; e < 4; ++e) wv[e] = *(const float4*)(&S[rowoff(wr) + e*sw + Jj + 4*tc]);
                wv[0].y = wv[0].z = wv[0].w = 0.f;
                wv[1].z = wv[1].w = 0.f;
                wv[2].w = 0.f;
                gemmacc(mt, lv, wv);
                for (int kk = k4 + 4; kk < NB; kk += 4) {
                    #pragma unroll
                    for (int r = 0; r < 4; ++r) lv[r] = *(const float4*)(&S[obase + r*so + Jj + kk]);
                    const int wr2 = Jj + kk;
                    const int sw2 = 4*((wr2 >> 2) + 1);
                    #pragma unroll
                    for (int e = 0; e < 4; ++e) wv[e] = *(const float4*)(&S[rowoff(wr2) + e*sw2 + Jj + 4*tc]);
                    gemmacc(mt, lv, wv);
                }
            }
            for (int k = jblk + 1; k < i; ++k) {   // full W blocks
                const int Jk = k * NB;
                #pragma unroll
                for (int k4 = 0; k4 < NB; k4 += 4) {
                    #pragma unroll
                    for (int r = 0; r < 4; ++r) lv[r] = *(const float4*)(&S[obase + r*so + Jk + k4]);
                    const int wr = Jk + k4;
                    const int sw = 4*((wr >> 2) + 1);
                    #pragma unroll
                    for (int e = 0; e < 4; ++e) wv[e] = *(const float4*)(&S[rowoff(wr) + e*sw + Jj + 4*tc]);
                    gemmacc(mt, lv, wv);
                }
            }
        }
        __syncthreads();                 // all reads of L row i done
        if (act) {
            #pragma unroll
            for (int r = 0; r < 4; ++r) {
                float4 o = {mt[r][0], mt[r][1], mt[r][2], mt[r][3]};
                *(float4*)(&S[obase + r*so + Jj + 4*tc]) = o;    // M over L_ij
            }
        }
        __syncthreads();
        float wt[4][4] = {{0,0,0,0},{0,0,0,0},{0,0,0,0},{0,0,0,0}};
        if (act) {
            float4 lv[4], mv[4];
            for (int k4 = 0; k4 < 4*tr; k4 += 4) {     // unmasked W_ii chunks
                #pragma unroll
                for (int r = 0; r < 4; ++r) lv[r] = *(const float4*)(&S[obase + r*so + Ji + k4]);
                const int mr = Ji + k4;
                const int sm = 4*((mr >> 2) + 1);
                #pragma unroll
                for (int e = 0; e < 4; ++e) mv[e] = *(const float4*)(&S[rowoff(mr) + e*sm + Jj + 4*tc]);
                gemmacc(wt, lv, mv);
            }
            {   // chunk k4 == 4*tr: W_ii row r valid lanes e <= r
                const int k4 = 4*tr;
                #pragma unroll
                for (int r = 0; r < 4; ++r) lv[r] = *(const float4*)(&S[obase + r*so + Ji + k4]);
                lv[0].y = lv[0].z = lv[0].w = 0.f;
                lv[1].z = lv[1].w = 0.f;
                lv[2].w = 0.f;
                const int mr = Ji + k4;
                const int sm = 4*((mr >> 2) + 1);
                #pragma unroll
                for (int e = 0; e < 4; ++e) mv[e] = *(const float4*)(&S[rowoff(mr) + e*sm + Jj + 4*tc]);
                gemmacc(wt, lv, mv);
            }
            #pragma unroll
            for (int c = 0; c < 4; ++c) {
                float part = 0.f;
                #pragma unroll
                for (int r = 0; r < 4; ++r) {
                    wt[r][c] = -wt[r][c];
                    part = fmaf(wt[r][c], wt[r][c], part);
                }
                atomicAdd(&colsum[Jj + 4*tc + c], part);
            }
        }
        __syncthreads();
        if (act) {
            #pragma unroll
            for (int r = 0; r < 4; ++r) {
                float4 o = {wt[r][0], wt[r][1], wt[r][2], wt[r][3]};
                *(float4*)(&S[obase + r*so + Jj + 4*tc]) = o;    // W over M
            }
        }
        __syncthreads();
    }

    if (tid < DD) winv[(size_t)tid * P + p] = 1.0f / colsum[tid];
}

// ---------------------------------------------------------------------------
// Kernel B: thread per (b,p); 2D grid (13x32=416 blocks) for latency hiding.
// ---------------------------------------------------------------------------
__global__ __launch_bounds__(256) void ace_kernel(
    const float* __restrict__ X,      // [B][D][P]
    const float* __restrict__ bmean,  // [D][P]
    const float* __restrict__ covs,   // [P][D][D] (ct==0 only)
    const float* __restrict__ sig,    // [D][P]
    const int*   __restrict__ ctp,
    const float* __restrict__ winv,   // [D][P]
    float*       __restrict__ out,    // [B][P]
    int B, int P)
{
    const int ct = *ctp;
    const int b = blockIdx.y;
    const int p = blockIdx.x * 256 + threadIdx.x;
    if (p >= P) return;

    const float eps = 1e-12f;

    if (ct == 0) {    // full-cov fallback (correctness path)
        float dot = 0.f, nx = 0.f, ns = 0.f;
        for (int m = 0; m < DD; ++m) {
            float xwm = 0.f;
            const float* crow = covs + (size_t)p * DD * DD + (size_t)m * DD;
            for (int d = 0; d < DD; ++d) {
                const float xc = X[((size_t)b * DD + d) * P + p] - bmean[(size_t)d * P + p];
                xwm = fmaf(xc, crow[d], xwm);
            }
            const float sg = sig[(size_t)m * P + p];
            nx = fmaf(xwm, xwm, nx); ns = fmaf(sg, sg, ns); dot = fmaf(xwm, sg, dot);
        }
        out[(size_t)b * P + p] = dot / (fmaxf(sqrtf(nx), eps) * fmaxf(sqrtf(ns), eps));
        return;
    }

    float dot = 0.f, nx = 0.f, ns = 0.f;
    const size_t bp = (size_t)b * DD * P + p;
    if (ct == 1) {
        #pragma unroll 8
        for (int d = 0; d < DD; ++d) {
            const float xc = X[bp + (size_t)d * P] - bmean[(size_t)d * P + p];
            const float xw = xc * winv[(size_t)d * P + p];
            const float sg = sig[(size_t)d * P + p];
            nx = fmaf(xw, xw, nx); ns = fmaf(sg, sg, ns); dot = fmaf(xw, sg, dot);
        }
    } else {          // ct == 2: positive scalar cancels under normalization
        #pragma unroll 8
        for (int d = 0; d < DD; ++d) {
            const float xc = X[bp + (size_t)d * P] - bmean[(size_t)d * P + p];
            const float sg = sig[(size_t)d * P + p];
            nx = fmaf(xc, xc, nx); ns = fmaf(sg, sg, ns); dot = fmaf(xc, sg, dot);
        }
    }
    out[(size_t)b * P + p] = dot / (fmaxf(sqrtf(nx), eps) * fmaxf(sqrtf(ns), eps));
}

// ---------------------------------------------------------------------------
extern "C" void kernel_launch(void* const* d_in, const int* in_sizes, int n_in,
                              void* d_out, int out_size, void* d_ws, size_t ws_size,
                              hipStream_t stream)
{
    const float* X     = (const float*)d_in[0];
    const float* bmean = (const float*)d_in[1];
    const float* covs  = (const float*)d_in[2];
    const float* sig   = (const float*)d_in[3];
    const int*   ctp   = (const int*)d_in[4];

    const int DP = in_sizes[1];       // D*P
    const int P  = DP / DD;           // 3136
    const int B  = in_sizes[0] / DP;  // 32

    float* winv = (float*)d_ws;       // [D][P] scratch

    diag_inv_kernel<<<P, NT, 0, stream>>>(covs, ctp, winv, P);

    dim3 gace((P + 255) / 256, B);
    ace_kernel<<<gace, 256, 0, stream>>>(
        X, bmean, covs, sig, ctp, winv, (float*)d_out, B, P);
}